// Round 6
// baseline (34.185 us; speedup 1.0000x reference)
//
#include <hip/hip_runtime.h>
#include <math.h>

#define BURN 36                  // burn-in months (coalescence margin)
#define BLK  64                  // threads/block = months emitted per block
#define PREP (BLK + BURN)        // months prepped per block (100)

// ---------------------------------------------------------------------------
// Day step, critical path = 3 dependent VALU ops, 13 VALU total.
//   depth1: t = fma(c2,P,c1) ; q = fma(ov,A,P) ; w = sdp*P ; bounds fmas
//   depth2: v = fma(-t,P,q)  ; a1 = fma(om,A,w) ; lo1/alo1 = max(lo,1)
//   depth3: P' = med3(v, lo1, hi) ; A' = med3(a1, alo1, ahi)
// Identity: max(min(max(v,lo),hi),1) == min(max(v,max(lo,1)),hi) since hi>=101.
// ---------------------------------------------------------------------------
__device__ __forceinline__ void day_step3(float& P, float& A,
                                          float c1, float c2, float sdp, float om,
                                          float ov) {
    float t    = fmaf(c2, P, c1);
    float q    = fmaf(ov, A, P);
    float w    = sdp * P;
    float lo   = fmaf(0.7f, P, -100.0f);
    float hi   = fmaf(1.3f, P,  100.0f);
    float alo  = fmaf(0.7f, A, -100.0f);
    float ahi  = fmaf(1.3f, A,  100.0f);
    float v    = fmaf(-t, P, q);             // P + dP (unclamped)
    float a1   = fmaf(om, A, w);             // A + dA (unclamped)
    float lo1  = fmaxf(lo,  1.0f);
    float alo1 = fmaxf(alo, 1.0f);
    P = fminf(fmaxf(v,  lo1),  hi);          // v_med3_f32
    A = fminf(fmaxf(a1, alo1), ahi);
}

__device__ __forceinline__ void month_step3(float& P, float& A, float4 c, float ov, int days) {
    const float c1 = c.x, c2 = c.y, sdp = c.z, om = c.w;
    if (days == 15) {
#pragma unroll
        for (int d = 0; d < 15; ++d) day_step3(P, A, c1, c2, sdp, om, ov);
    } else {
        for (int d = 0; d < days; ++d) day_step3(P, A, c1, c2, sdp, om, ov);
    }
}

// fast tanh: 1 - 2/(exp2(2x*log2e)+1); ~2 ulp, v_exp + v_rcp + 3 VALU
__device__ __forceinline__ float fast_tanh(float x) {
    float e = __builtin_exp2f(x * 2.8853900817779268f);
    return fmaf(-2.0f, __builtin_amdgcn_rcpf(e + 1.0f), 1.0f);
}

// ---------------------------------------------------------------------------
// Fused kernel. Block b owns months [64b, 64b+64).
// Phase 1: prep months [64b-BURN, 64b+64) into LDS (MLP ovi + scan consts).
// Phase 2: each lane c runs BURN+1 months; lanes c<=BURN start exact at month
// 0 (true init); others start at month c-BURN from the floor state (1,1) —
// floors + strong mortality + attracting bloom equilibria coalesce the
// speculative trajectory onto the true one within the burn-in.
// ---------------------------------------------------------------------------
__global__ __launch_bounds__(BLK)
void mosq_fused(const float* __restrict__ wn, const float* __restrict__ wr,
                const float* __restrict__ W1, const float* __restrict__ b1,
                const float* __restrict__ W2, const float* __restrict__ b2,
                const float* __restrict__ lsig, const float* __restrict__ lK,
                const float* __restrict__ lP0, const float* __restrict__ lA0,
                const int* __restrict__ dptr,
                float* __restrict__ Aout, float* __restrict__ Pout,
                float* __restrict__ ovi_out, int n, int H) {
    __shared__ float4 sc[PREP];
    __shared__ float  sov[PREP];

    const int t    = threadIdx.x;
    const int base = blockIdx.x * BLK - BURN;   // absolute month of LDS slot 0

    const float K     = expf(lK[0]) * 1000000.0f;
    const float sigma = 1.0f / (1.0f + expf(-lsig[0]));

    // ---- Phase 1: in-block prep (1-2 months per thread) ----
    for (int k = t; k < PREP; k += BLK) {
        int m  = base + k;
        int mc = m < 0 ? 0 : (m >= n ? n - 1 : m);   // clamp (slots <0 unused)
        float x0 = wn[3 * mc + 0];
        float x1 = wn[3 * mc + 1];
        float x2 = wn[3 * mc + 2];
        float acc = b2[0];
        for (int j = 0; j < H; ++j) {
            float pre = fmaf(x0, W1[j], fmaf(x1, W1[H + j], fmaf(x2, W1[2 * H + j], b1[j])));
            acc = fmaf(fast_tanh(pre), W2[j], acc);
        }
        float T  = wr[3 * mc];
        float r  = (T - 27.0f) / 9.0f;
        float dp = fmaxf(0.08f * expf(-(r * r)), 0.005f);
        float t1 = T - 26.0f;
        float ma = fmaf(0.002f, t1 * t1, 0.03f);
        float t2 = T - 22.0f;
        float mp = fmaf(0.003f, t2 * t2, 0.05f);

        sc[k]  = make_float4(dp + mp, mp / K, sigma * dp, 1.0f - ma);
        sov[k] = acc;
        if (k >= BURN && m < n) ovi_out[m] = acc;    // own months only, once
    }
    __syncthreads();

    // ---- Phase 2: speculative scan, one emitted month per lane ----
    const int c    = blockIdx.x * BLK + t;   // month owned by this lane
    const int days = dptr[0];

    int   emit_j, s0;
    float P, A;
    if (c <= BURN) {                 // block 0 only: exact prefix
        emit_j = c;
        s0     = BURN;               // month 0 -> slot 0 - base = BURN
        P = expf(lP0[0]) * 1000.0f;
        A = expf(lA0[0]) * 100.0f;
    } else {
        emit_j = BURN;
        s0     = t;                  // month c-BURN -> slot t
        P = 1.0f;
        A = 1.0f;
    }

    float Aem = 0.0f, Pem = 0.0f;
    float4 cc = sc[s0];
    float  oo = sov[s0];
    for (int j = 0; j <= BURN; ++j) {
        int sn = s0 + j + 1;
        sn = sn < PREP ? sn : PREP - 1;      // prefetch clamp (value unused)
        float4 cnx = sc[sn];
        float  onx = sov[sn];

        month_step3(P, A, cc, oo, days);

        bool em = (j == emit_j);
        Aem = em ? A : Aem;                  // v_cndmask latch
        Pem = em ? P : Pem;

        cc = cnx; oo = onx;
    }
    if (c < n) {
        Aout[c] = Aem;
        Pout[c] = Pem;
    }
}

// ---------------------------------------------------------------------------
extern "C" void kernel_launch(void* const* d_in, const int* in_sizes, int n_in,
                              void* d_out, int out_size, void* d_ws, size_t ws_size,
                              hipStream_t stream) {
    const float* wn   = (const float*)d_in[0];   // weather_norm (n,3)
    const float* wr   = (const float*)d_in[1];   // weather_raw  (n,3)
    const float* W1   = (const float*)d_in[2];   // (3,H)
    const float* b1   = (const float*)d_in[3];   // (H,)
    const float* W2   = (const float*)d_in[4];   // (H,1)
    const float* b2   = (const float*)d_in[5];   // (1,)
    const float* lsig = (const float*)d_in[6];
    const float* lK   = (const float*)d_in[7];
    const float* lP0  = (const float*)d_in[8];
    const float* lA0  = (const float*)d_in[9];
    const int*   dps  = (const int*)d_in[10];

    const int n = in_sizes[0] / 3;
    const int H = in_sizes[3];

    float* out     = (float*)d_out;
    float* Aout    = out;             // A_series
    float* Pout    = out + n;         // P_series
    float* ovi_out = out + 2 * n;     // ovi

    const int blocks = (n + BLK - 1) / BLK;      // 128 for n=8192
    mosq_fused<<<blocks, BLK, 0, stream>>>(wn, wr, W1, b1, W2, b2, lsig, lK,
                                           lP0, lA0, dps,
                                           Aout, Pout, ovi_out, n, H);
}

// Round 7
// 23.731 us; speedup vs baseline: 1.4405x; 1.4405x over previous
//
#include <hip/hip_runtime.h>
#include <math.h>

#define BURN 33     // burn-in months (coalescence margin)

typedef float v2f __attribute__((ext_vector_type(2)));

// ---------------------------------------------------------------------------
// Phase A: per-month parallel precompute, 8 threads per month.
//   ovi[i] = tanh(wn[i,:] @ W1 + b1) @ W2 + b2
//   pack per-month scan constants: c1 = dp+mp, c2 = mp/K, sdp = sigma*dp, om = 1-ma
// Writes n+2 entries (last two are sentinels = copies of month n-1) so the
// scan's prefetch needs no index clamping.
// ---------------------------------------------------------------------------
__global__ void mosq_prep8(const float* __restrict__ wn, const float* __restrict__ wr,
                           const float* __restrict__ W1, const float* __restrict__ b1,
                           const float* __restrict__ W2, const float* __restrict__ b2,
                           const float* __restrict__ log_sigma, const float* __restrict__ log_K,
                           float4* __restrict__ c4, float* __restrict__ ovi_ws,
                           float* __restrict__ ovi_out, int n, int H) {
    int t = blockIdx.x * blockDim.x + threadIdx.x;
    int i    = t >> 3;        // padded month index (0 .. n+1)
    int lane = t & 7;         // 8 lanes per month
    if (i >= n + 2) return;
    int mc = i < n ? i : n - 1;   // sentinel entries replicate last month

    float x0 = wn[3 * mc + 0];
    float x1 = wn[3 * mc + 1];
    float x2 = wn[3 * mc + 2];

    int j0 = lane * (H >> 3);
    int j1 = j0 + (H >> 3);
    float acc = 0.0f;
    for (int j = j0; j < j1; ++j) {
        float pre = fmaf(x0, W1[j], fmaf(x1, W1[H + j], fmaf(x2, W1[2 * H + j], b1[j])));
        acc += tanhf(pre) * W2[j];
    }
    // reduce across the 8 lanes of this month
    acc += __shfl_xor(acc, 1, 8);
    acc += __shfl_xor(acc, 2, 8);
    acc += __shfl_xor(acc, 4, 8);

    if (lane == 0) {
        acc += b2[0];

        float T  = wr[3 * mc];
        float r  = (T - 27.0f) / 9.0f;
        float dp = fmaxf(0.08f * expf(-(r * r)), 0.005f);
        float t1 = T - 26.0f;
        float ma = fmaf(0.002f, t1 * t1, 0.03f);
        float t2 = T - 22.0f;
        float mp = fmaf(0.003f, t2 * t2, 0.05f);

        float K     = expf(log_K[0]) * 1000000.0f;
        float sigma = 1.0f / (1.0f + expf(-log_sigma[0]));

        // c1 = dp+mp, c2 = mp/K, sdp = sigma*dp, om = 1-ma
        c4[i]     = make_float4(dp + mp, mp / K, sigma * dp, 1.0f - ma);
        ovi_ws[i] = acc;
        if (i < n) ovi_out[i] = acc;
    }
}

// ---------------------------------------------------------------------------
// Day step. 11-13 VALU, critical path 3 dependent ops.
//   bounds for (P,A) computed as packed-f32 pairs (v_pk_fma_f32):
//     lo = 0.7*PA - 100 ; hi = 1.3*PA + 100 ; lo1 = max(lo, 1)
//   dynamics scalar:
//     t = fma(c2,P,c1); q = fma(ov,A,P); v = fma(-t,P,q)      (P + dP)
//     a1 = fma(om,A,sdp*P)                                     (A + dA)
//   clamp+floor fused: X' = med3(x, max(loX,1), hiX)   (valid: hi >= 101 > 1)
// ---------------------------------------------------------------------------
__device__ __forceinline__ void day_step4(v2f& PA, float c1, float c2,
                                          float sdp, float om, float ov) {
    const v2f k07   = {0.7f, 0.7f};
    const v2f km100 = {-100.0f, -100.0f};
    const v2f k13   = {1.3f, 1.3f};
    const v2f k100  = {100.0f, 100.0f};

    float P = PA.x, A = PA.y;
    v2f lo = PA * k07 + km100;      // contracts to v_pk_fma_f32
    v2f hi = PA * k13 + k100;
    float t   = fmaf(c2, P, c1);
    float q   = fmaf(ov, A, P);
    float w   = sdp * P;
    float v   = fmaf(-t, P, q);     // P + dP (unclamped)
    float a1  = fmaf(om, A, w);     // A + dA (unclamped)
    float lo1  = fmaxf(lo.x, 1.0f);
    float alo1 = fmaxf(lo.y, 1.0f);
    PA.x = fminf(fmaxf(v,  lo1),  hi.x);    // v_med3_f32
    PA.y = fminf(fmaxf(a1, alo1), hi.y);
}

__device__ __forceinline__ void month_step4(v2f& PA, float4 c, float ov, int days) {
    const float c1 = c.x, c2 = c.y, sdp = c.z, om = c.w;
    if (days == 15) {
#pragma unroll
        for (int d = 0; d < 15; ++d) day_step4(PA, c1, c2, sdp, om, ov);
    } else {
        for (int d = 0; d < days; ++d) day_step4(PA, c1, c2, sdp, om, ov);
    }
}

// ---------------------------------------------------------------------------
// Phase B: speculative scan, ONE month emitted per lane.
// Lane c > BURN runs months [c-BURN, c] from the floor state (1,1); floors +
// strong per-day mortality + attracting bloom equilibria coalesce the
// speculative trajectory onto the true one within the burn-in, and the
// emitted month is simply the LAST iteration (no latch needed).
// Lanes c <= BURN run months [0, c] from the TRUE initial state (exact).
// Loads are coalesced: consecutive lanes read consecutive months.
// ---------------------------------------------------------------------------
__global__ __launch_bounds__(64)
void mosq_scan3(const float4* __restrict__ c4, const float* __restrict__ ovi,
                const float* __restrict__ log_P0, const float* __restrict__ log_A0,
                const int* __restrict__ dptr,
                float* __restrict__ Aout, float* __restrict__ Pout, int n) {
    int c = blockIdx.x * blockDim.x + threadIdx.x;   // month owned by this lane
    if (c >= n) return;
    const int days = dptr[0];

    int   start, total;
    v2f   PA;
    if (c <= BURN) {                 // block 0 prefix: exact from true init
        start = 0;
        total = c + 1;
        PA.x  = expf(log_P0[0]) * 1000.0f;
        PA.y  = expf(log_A0[0]) * 100.0f;
    } else {
        start = c - BURN;
        total = BURN + 1;
        PA.x  = 1.0f;
        PA.y  = 1.0f;
    }

    // 1-deep register prefetch; sentinel entries make start+j+1 <= n+1 safe
    float4 cc = c4[start];
    float  oo = ovi[start];
    for (int j = 0; j < total; ++j) {
        float4 cn = c4[start + j + 1];
        float  on = ovi[start + j + 1];

        month_step4(PA, cc, oo, days);

        cc = cn; oo = on;
    }
    Aout[c] = PA.y;     // final state == emitted month c
    Pout[c] = PA.x;
}

// ---------------------------------------------------------------------------
extern "C" void kernel_launch(void* const* d_in, const int* in_sizes, int n_in,
                              void* d_out, int out_size, void* d_ws, size_t ws_size,
                              hipStream_t stream) {
    const float* wn   = (const float*)d_in[0];   // weather_norm (n,3)
    const float* wr   = (const float*)d_in[1];   // weather_raw  (n,3)
    const float* W1   = (const float*)d_in[2];   // (3,H)
    const float* b1   = (const float*)d_in[3];   // (H,)
    const float* W2   = (const float*)d_in[4];   // (H,1)
    const float* b2   = (const float*)d_in[5];   // (1,)
    const float* lsig = (const float*)d_in[6];
    const float* lK   = (const float*)d_in[7];
    const float* lP0  = (const float*)d_in[8];
    const float* lA0  = (const float*)d_in[9];
    const int*   dps  = (const int*)d_in[10];

    const int n = in_sizes[0] / 3;
    const int H = in_sizes[3];

    float* out     = (float*)d_out;
    float* Aout    = out;             // A_series
    float* Pout    = out + n;         // P_series
    float* ovi_out = out + 2 * n;     // ovi

    float4* c4     = (float4*)d_ws;                                   // (n+2)*16 B
    float*  ovi_ws = (float*)((char*)d_ws + (size_t)(n + 2) * 16);    // (n+2)*4 B

    const int threads = 256;
    const int pblocks = (8 * (n + 2) + threads - 1) / threads;
    mosq_prep8<<<pblocks, threads, 0, stream>>>(wn, wr, W1, b1, W2, b2, lsig, lK,
                                                c4, ovi_ws, ovi_out, n, H);

    const int sthreads = 64;                               // one wave per block
    const int sblocks  = (n + sthreads - 1) / sthreads;    // 128 blocks for n=8192
    mosq_scan3<<<sblocks, sthreads, 0, stream>>>(c4, ovi_ws, lP0, lA0, dps,
                                                 Aout, Pout, n);
}